// Round 1
// baseline (212.653 us; speedup 1.0000x reference)
//
#include <hip/hip_runtime.h>
#include <cstdint>
#include <cstddef>

typedef short bf16x8 __attribute__((ext_vector_type(8)));
typedef float f32x4 __attribute__((ext_vector_type(4)));

#define EPS 1e-3f

__device__ __forceinline__ short f32_to_bf16s(float f) {
    union { float f; uint32_t u; } v; v.f = f;
    return (short)((v.u + 0x7FFFu + ((v.u >> 16) & 1u)) >> 16);
}

// K0: wt[kp][ci] = bf16(W[ci][kp]) (192x64); at[w][k] = bf16(A[p][v][w]) (32x96, k=p*25+v, zero-padded)
__global__ __launch_bounds__(256) void prep_kernel(const float* __restrict__ A,
                                                   const float* __restrict__ W,
                                                   unsigned short* __restrict__ wt,
                                                   unsigned short* __restrict__ at) {
    int idx = blockIdx.x * 256 + threadIdx.x;
    if (idx < 12288) {
        int kp = idx >> 6, ci = idx & 63;
        wt[idx] = (unsigned short)f32_to_bf16s(W[ci * 192 + kp]);
    } else {
        int j = idx - 12288;
        if (j < 3072) {
            int w = j / 96, k = j - w * 96;
            float val = 0.f;
            if (w < 25 && k < 75) {
                int p = k / 25, v = k - p * 25;
                val = A[(p * 25 + v) * 25 + w];
            }
            at[j] = (unsigned short)f32_to_bf16s(val);
        }
    }
}

// ---- phase-1 helpers: issue (global loads), pack (window sums -> 4 packed bf16 dwords),
// ---- write (scatter into xwL).  Arithmetic is identical to the previous kernel's loop.
__device__ __forceinline__ void p1_issue(const float* __restrict__ xn, int l0, int cidx,
                                         bool act, float* v16) {
    int ci = cidx / 25, v = cidx - ci * 25;
    const float* xp = xn + (size_t)ci * 7500 + v;
    #pragma unroll
    for (int i = 0; i < 16; ++i) {
        int l = l0 - 8 + i;
        v16[i] = (act && l >= 0 && l < 300) ? xp[l * 25] : 0.f;
    }
}

__device__ __forceinline__ void p1_pack(const float* v16, uint32_t* pk) {
    float run = v16[0] + v16[1] + v16[2] + v16[3] + v16[4] + v16[5] + v16[6] + v16[7];
    #pragma unroll
    for (int jj = 0; jj < 4; ++jj) {
        run += v16[2 * jj + 8];
        uint32_t lo = (uint32_t)(unsigned short)f32_to_bf16s(run);
        run -= v16[2 * jj];
        run += v16[2 * jj + 9];
        uint32_t hi = (uint32_t)(unsigned short)f32_to_bf16s(run);
        run -= v16[2 * jj + 1];
        pk[jj] = lo | (hi << 16);
    }
}

__device__ __forceinline__ void p1_write(short* smem, int cidx, const uint32_t* pk) {
    int ci = cidx / 25, v = cidx - ci * 25;
    short* wb = &smem[(ci >> 3) * 1656 + (ci & 7) + v * 8];
    #pragma unroll
    for (int jj = 0; jj < 4; ++jj) {
        wb[(2 * jj) * 200]     = (short)(pk[jj] & 0xFFFF);
        wb[(2 * jj + 1) * 200] = (short)(pk[jj] >> 16);
    }
}

// ---- one output c-group: GEMM1 (W^T x xw), stage to Ys slab, GEMM2 (x A), BN+res epilogue
__device__ __forceinline__ void do_group(int g, const unsigned short* __restrict__ wt,
    short* smem, const bf16x8 (&b1)[2][2], const bf16x8 (&b2)[2][3],
    const float* __restrict__ xn, float* __restrict__ outn,
    const float* scs, const float* shs,
    int lg, int wv, int q, int lcol)
{
    bf16x8 a1[3][2];
    #pragma unroll
    for (int mt = 0; mt < 3; ++mt)
        #pragma unroll
        for (int s = 0; s < 2; ++s)
            a1[mt][s] = *(const bf16x8*)(wt + (size_t)(g * 48 + mt * 16 + lcol) * 64 + 32 * s + 8 * q);

    f32x4 acc[3][2];
    #pragma unroll
    for (int mt = 0; mt < 3; ++mt)
        #pragma unroll
        for (int nt = 0; nt < 2; ++nt) acc[mt][nt] = (f32x4){0.f, 0.f, 0.f, 0.f};
    #pragma unroll
    for (int s = 0; s < 2; ++s)
        #pragma unroll
        for (int mt = 0; mt < 3; ++mt) {
            bf16x8 av = a1[mt][s];
            #pragma unroll
            for (int nt = 0; nt < 2; ++nt)
                acc[mt][nt] = __builtin_amdgcn_mfma_f32_16x16x32_bf16(av, b1[nt][s], acc[mt][nt], 0, 0, 0);
        }

    // residual prefetch (L2-hot: rows read by this block's phase-1 / prefetch)
    const size_t rbase = (size_t)lg * 25;
    float res[2][4];
    #pragma unroll
    for (int nt = 0; nt < 2; ++nt) {
        int w = nt * 16 + lcol;
        bool val = (w < 25) && (lg < 300);
        #pragma unroll
        for (int r = 0; r < 4; ++r) {
            int c = g * 16 + 4 * q + r;
            res[nt][r] = val ? xn[rbase + (size_t)c * 7500 + w] : 0.f;
        }
    }

    // stage D -> own Ys slab (wave-private, no barrier; compiler orders via lgkmcnt)
    #pragma unroll
    for (int mt = 0; mt < 3; ++mt)
        #pragma unroll
        for (int nt = 0; nt < 2; ++nt) {
            int v = nt * 16 + lcol;
            if (v < 25) {
                #pragma unroll
                for (int r = 0; r < 4; ++r) {
                    int kpl = mt * 16 + 4 * q + r;
                    int cl = kpl / 3, p = kpl - 3 * cl;
                    smem[(wv * 16 + cl) * 104 + 25 * p + v] = f32_to_bf16s(acc[mt][nt][r]);
                }
            }
        }

    f32x4 c0 = {0.f, 0.f, 0.f, 0.f}, c1 = {0.f, 0.f, 0.f, 0.f};
    #pragma unroll
    for (int s = 0; s < 3; ++s) {
        bf16x8 a2 = *(const bf16x8*)&smem[(wv * 16 + lcol) * 104 + 32 * s + 8 * q];
        c0 = __builtin_amdgcn_mfma_f32_16x16x32_bf16(a2, b2[0][s], c0, 0, 0, 0);
        c1 = __builtin_amdgcn_mfma_f32_16x16x32_bf16(a2, b2[1][s], c1, 0, 0, 0);
    }

    if (lg < 300) {
        #pragma unroll
        for (int nt = 0; nt < 2; ++nt) {
            int w = nt * 16 + lcol;
            if (w < 25) {
                f32x4 cc = nt ? c1 : c0;
                #pragma unroll
                for (int r = 0; r < 4; ++r) {
                    int c = g * 16 + 4 * q + r;
                    float o = fmaxf(cc[r] * scs[c] + shs[c], 0.f);
                    outn[rbase + (size_t)c * 7500 + w] = fmaxf(o + res[nt][r], 0.f);
                }
            }
        }
    }
}

// Mega v2: block = (l-chunk of 8, n-pair). Grid 38x16 = 608 blocks -> all resident at
// t=0 (no dispatch tail). n1's phase-1 global loads are issued between n0's GEMM
// groups (T14 issue-early/write-late): HBM latency hides under MFMA/VALU; only the
// cheap LDS scatter of pre-packed bf16 results remains after the barrier.
// Barriers: B1 xwL(n0) ready | B2 b1(n0) read | B3 Ys(n0) done | B4 xwL(n1) ready | B5 b1(n1) read.
__global__ __launch_bounds__(512, 4) void mega_kernel(
    const float* __restrict__ x,
    const unsigned short* __restrict__ wt,
    const unsigned short* __restrict__ at,
    const float* __restrict__ gamma, const float* __restrict__ beta,
    const float* __restrict__ mean, const float* __restrict__ var,
    float* __restrict__ out) {
    const int ch = blockIdx.x;
    const int n0 = blockIdx.y * 2;
    const int l0 = ch * 8;
    const int tid = threadIdx.x;
    const int wv = tid >> 6, lane = tid & 63, q = lane >> 4, lcol = lane & 15;

    __shared__ __align__(16) short smem[13312];   // xwL (13248) aliased with Ys (13312)
    __shared__ float scs[64], shs[64];

    const float* xn0 = x + (size_t)n0 * 480000;
    const float* xn1 = xn0 + 480000;
    float* outn0 = out + (size_t)n0 * 480000;
    float* outn1 = outn0 + 480000;

    // b2 fragments (at, L2-resident) + BN constants
    bf16x8 b2[2][3];
    #pragma unroll
    for (int nt = 0; nt < 2; ++nt)
        #pragma unroll
        for (int s = 0; s < 3; ++s)
            b2[nt][s] = *(const bf16x8*)(at + (size_t)(nt * 16 + lcol) * 96 + 32 * s + 8 * q);
    if (tid < 64) {
        float sc = gamma[tid] * rsqrtf(var[tid] + EPS);
        scs[tid] = sc;
        shs[tid] = beta[tid] - mean[tid] * sc;
    }

    // Phase 1 for n0 (load -> window -> write, as before)
    #pragma unroll 1
    for (int rep = 0; rep < 4; ++rep) {
        int cidx = tid + rep * 512;
        bool act = cidx < 1600;
        float t16[16]; uint32_t tpk[4];
        p1_issue(xn0, l0, cidx, act, t16);
        p1_pack(t16, tpk);
        if (act) p1_write(smem, cidx, tpk);
    }

    // early-issue rep0 of n1's phase-1 (registers only; lands during b1 load + group 0)
    float v16[16];
    uint32_t pk0[4], pk1[4], pk2[4], pk3[4];
    p1_issue(xn1, l0, tid, true, v16);

    __syncthreads();   // B1: xwL(n0) ready

    bf16x8 b1[2][2];
    #pragma unroll
    for (int nt = 0; nt < 2; ++nt) {
        int col = wv * 25 + nt * 16 + lcol;
        #pragma unroll
        for (int s = 0; s < 2; ++s)
            b1[nt][s] = *(const bf16x8*)&smem[(4 * s + q) * 1656 + col * 8];
    }
    __syncthreads();   // B2: xwL reads done; smem becomes Ys

    #pragma unroll
    for (int i = lane; i < 512; i += 64) {
        int r = i >> 5, cc = 72 + (i & 31);
        smem[(wv * 16 + r) * 104 + cc] = 0;
    }

    const int lg = l0 + wv;

    // n0 GEMM groups, n1 phase-1 pipelined between them
    do_group(0, wt, smem, b1, b2, xn0, outn0, scs, shs, lg, wv, q, lcol);
    p1_pack(v16, pk0);
    p1_issue(xn1, l0, tid + 512, true, v16);
    do_group(1, wt, smem, b1, b2, xn0, outn0, scs, shs, lg, wv, q, lcol);
    p1_pack(v16, pk1);
    p1_issue(xn1, l0, tid + 1024, true, v16);
    do_group(2, wt, smem, b1, b2, xn0, outn0, scs, shs, lg, wv, q, lcol);
    p1_pack(v16, pk2);
    p1_issue(xn1, l0, tid + 1536, tid < 64, v16);
    do_group(3, wt, smem, b1, b2, xn0, outn0, scs, shs, lg, wv, q, lcol);
    p1_pack(v16, pk3);

    __syncthreads();   // B3: all Ys(n0) reads done; smem becomes xwL(n1)

    p1_write(smem, tid, pk0);
    p1_write(smem, tid + 512, pk1);
    p1_write(smem, tid + 1024, pk2);
    if (tid < 64) p1_write(smem, tid + 1536, pk3);

    __syncthreads();   // B4: xwL(n1) ready

    #pragma unroll
    for (int nt = 0; nt < 2; ++nt) {
        int col = wv * 25 + nt * 16 + lcol;
        #pragma unroll
        for (int s = 0; s < 2; ++s)
            b1[nt][s] = *(const bf16x8*)&smem[(4 * s + q) * 1656 + col * 8];
    }
    __syncthreads();   // B5: xwL(n1) reads done; smem becomes Ys again

    #pragma unroll
    for (int i = lane; i < 512; i += 64) {
        int r = i >> 5, cc = 72 + (i & 31);
        smem[(wv * 16 + r) * 104 + cc] = 0;
    }

    #pragma unroll 1
    for (int g = 0; g < 4; ++g)
        do_group(g, wt, smem, b1, b2, xn1, outn1, scs, shs, lg, wv, q, lcol);
}

extern "C" void kernel_launch(void* const* d_in, const int* in_sizes, int n_in,
                              void* d_out, int out_size, void* d_ws, size_t ws_size,
                              hipStream_t stream) {
    const float* x     = (const float*)d_in[0];
    const float* A     = (const float*)d_in[1];
    const float* W     = (const float*)d_in[2];
    const float* gamma = (const float*)d_in[3];
    const float* beta  = (const float*)d_in[4];
    const float* mean  = (const float*)d_in[5];
    const float* var   = (const float*)d_in[6];
    float* out = (float*)d_out;

    char* ws = (char*)d_ws;
    unsigned short* wt = (unsigned short*)ws;               // 24,576 B
    unsigned short* at = (unsigned short*)(ws + 24576);     // 6,144 B

    prep_kernel<<<60, 256, 0, stream>>>(A, W, wt, at);
    mega_kernel<<<dim3(38, 16), 512, 0, stream>>>(x, wt, at, gamma, beta, mean, var, out);
}

// Round 2
// 182.712 us; speedup vs baseline: 1.1639x; 1.1639x over previous
//
#include <hip/hip_runtime.h>
#include <cstdint>
#include <cstddef>

typedef short bf16x8 __attribute__((ext_vector_type(8)));
typedef float f32x4 __attribute__((ext_vector_type(4)));

#define EPS 1e-3f

__device__ __forceinline__ short f32_to_bf16s(float f) {
    union { float f; uint32_t u; } v; v.f = f;
    return (short)((v.u + 0x7FFFu + ((v.u >> 16) & 1u)) >> 16);
}

// K0: wt[kp][ci] = bf16(W[ci][kp]) (192x64); at[w][k] = bf16(A[p][v][w]) (32x96, k=p*25+v, zero-padded)
__global__ __launch_bounds__(256) void prep_kernel(const float* __restrict__ A,
                                                   const float* __restrict__ W,
                                                   unsigned short* __restrict__ wt,
                                                   unsigned short* __restrict__ at) {
    int idx = blockIdx.x * 256 + threadIdx.x;
    if (idx < 12288) {
        int kp = idx >> 6, ci = idx & 63;
        wt[idx] = (unsigned short)f32_to_bf16s(W[ci * 192 + kp]);
    } else {
        int j = idx - 12288;
        if (j < 3072) {
            int w = j / 96, k = j - w * 96;
            float val = 0.f;
            if (w < 25 && k < 75) {
                int p = k / 25, v = k - p * 25;
                val = A[(p * 25 + v) * 25 + w];
            }
            at[j] = (unsigned short)f32_to_bf16s(val);
        }
    }
}

// ---- one output c-group: GEMM1 (W^T x xw), stage to Ys slab, GEMM2 (x A), BN+res epilogue
__device__ __forceinline__ void do_group(int g, const unsigned short* __restrict__ wt,
    short* smem, const bf16x8 (&b1)[2][2], const bf16x8 (&b2)[2][3],
    const float* __restrict__ xn, float* __restrict__ outn,
    const float* scs, const float* shs,
    int lg, int wv, int q, int lcol)
{
    bf16x8 a1[3][2];
    #pragma unroll
    for (int mt = 0; mt < 3; ++mt)
        #pragma unroll
        for (int s = 0; s < 2; ++s)
            a1[mt][s] = *(const bf16x8*)(wt + (size_t)(g * 48 + mt * 16 + lcol) * 64 + 32 * s + 8 * q);

    f32x4 acc[3][2];
    #pragma unroll
    for (int mt = 0; mt < 3; ++mt)
        #pragma unroll
        for (int nt = 0; nt < 2; ++nt) acc[mt][nt] = (f32x4){0.f, 0.f, 0.f, 0.f};
    #pragma unroll
    for (int s = 0; s < 2; ++s)
        #pragma unroll
        for (int mt = 0; mt < 3; ++mt) {
            bf16x8 av = a1[mt][s];
            #pragma unroll
            for (int nt = 0; nt < 2; ++nt)
                acc[mt][nt] = __builtin_amdgcn_mfma_f32_16x16x32_bf16(av, b1[nt][s], acc[mt][nt], 0, 0, 0);
        }

    // residual: L2-hot now (same XCD fetched these rows in phase-1; out stores are nt)
    const size_t rbase = (size_t)lg * 25;
    float res[2][4];
    #pragma unroll
    for (int nt = 0; nt < 2; ++nt) {
        int w = nt * 16 + lcol;
        bool val = (w < 25) && (lg < 300);
        #pragma unroll
        for (int r = 0; r < 4; ++r) {
            int c = g * 16 + 4 * q + r;
            res[nt][r] = val ? xn[rbase + (size_t)c * 7500 + w] : 0.f;
        }
    }

    // stage D -> own Ys slab (wave-private, no barrier; compiler orders via lgkmcnt)
    #pragma unroll
    for (int mt = 0; mt < 3; ++mt)
        #pragma unroll
        for (int nt = 0; nt < 2; ++nt) {
            int v = nt * 16 + lcol;
            if (v < 25) {
                #pragma unroll
                for (int r = 0; r < 4; ++r) {
                    int kpl = mt * 16 + 4 * q + r;
                    int cl = kpl / 3, p = kpl - 3 * cl;
                    smem[(wv * 16 + cl) * 104 + 25 * p + v] = f32_to_bf16s(acc[mt][nt][r]);
                }
            }
        }

    f32x4 c0 = {0.f, 0.f, 0.f, 0.f}, c1 = {0.f, 0.f, 0.f, 0.f};
    #pragma unroll
    for (int s = 0; s < 3; ++s) {
        bf16x8 a2 = *(const bf16x8*)&smem[(wv * 16 + lcol) * 104 + 32 * s + 8 * q];
        c0 = __builtin_amdgcn_mfma_f32_16x16x32_bf16(a2, b2[0][s], c0, 0, 0, 0);
        c1 = __builtin_amdgcn_mfma_f32_16x16x32_bf16(a2, b2[1][s], c1, 0, 0, 0);
    }

    if (lg < 300) {
        #pragma unroll
        for (int nt = 0; nt < 2; ++nt) {
            int w = nt * 16 + lcol;
            if (w < 25) {
                f32x4 cc = nt ? c1 : c0;
                #pragma unroll
                for (int r = 0; r < 4; ++r) {
                    int c = g * 16 + 4 * q + r;
                    float o = fmaxf(cc[r] * scs[c] + shs[c], 0.f);
                    // nontemporal: don't evict the x lines residual reads need
                    __builtin_nontemporal_store(fmaxf(o + res[nt][r], 0.f),
                                                &outn[rbase + (size_t)c * 7500 + w]);
                }
            }
        }
    }
}

// ---- full pipeline for one sample: phase-1 window -> xwL, GEMM1/2 groups, epilogue.
// No cross-sample register state (the v2 spill lesson): strictly sequential halves.
__device__ __forceinline__ void process_sample(
    const float* __restrict__ xn, float* __restrict__ outn,
    const unsigned short* __restrict__ wt,
    short* smem, const bf16x8 (&b2)[2][3],
    const float* scs, const float* shs,
    int l0, int tid, int wv, int lane, int q, int lcol)
{
    // Phase 1: per-(ci,v) running 9-window over l = l0..l0+7 -> xwL (bf16)
    #pragma unroll 1
    for (int rep = 0; rep < 4; ++rep) {
        int cidx = tid + rep * 512;
        if (cidx < 1600) {
            int ci = cidx / 25, v = cidx - ci * 25;
            const float* xp = xn + (size_t)ci * 7500 + v;
            float vals[16];
            #pragma unroll
            for (int i = 0; i < 16; ++i) {
                int l = l0 - 8 + i;
                vals[i] = (l >= 0 && l < 300) ? xp[l * 25] : 0.f;
            }
            float run = vals[0] + vals[1] + vals[2] + vals[3]
                      + vals[4] + vals[5] + vals[6] + vals[7];
            short* wb = &smem[(ci >> 3) * 1656 + (ci & 7)];
            #pragma unroll
            for (int j = 0; j < 8; ++j) {
                run += vals[j + 8];
                wb[(j * 25 + v) * 8] = f32_to_bf16s(run);
                run -= vals[j];
            }
        }
    }
    __syncthreads();   // B1: xwL ready

    // b1 fragments: B[k=ci][col], cols wv*25 + nt*16 + lcol (<=206; cols>=200 are
    // stale-but-finite garbage whose D-columns map to w>=25 and are never stored)
    bf16x8 b1[2][2];
    #pragma unroll
    for (int nt = 0; nt < 2; ++nt) {
        int col = wv * 25 + nt * 16 + lcol;
        #pragma unroll
        for (int s = 0; s < 2; ++s)
            b1[nt][s] = *(const bf16x8*)&smem[(4 * s + q) * 1656 + col * 8];
    }
    __syncthreads();   // B2: all xwL reads done; smem becomes Ys

    // Zero own Ys slab pad cols [72,104): wave-private from here on.
    #pragma unroll
    for (int i = lane; i < 512; i += 64) {
        int r = i >> 5, cc = 72 + (i & 31);
        smem[(wv * 16 + r) * 104 + cc] = 0;
    }

    const int lg = l0 + wv;
    #pragma unroll 1
    for (int g = 0; g < 4; ++g)
        do_group(g, wt, smem, b1, b2, xn, outn, scs, shs, lg, wv, q, lcol);
}

// Mega v3: pair-block (2 samples, sequential) -> grid 608 <= 1024 resident, no tail.
// XCD-chunked swizzle: XCD k owns logical ids [76k,76k+76) = all 38 ch of 2 samples
// -> per-XCD x working set 3.75 MB < 4 MB L2: halo fetched once, residual L2-hits.
__global__ __launch_bounds__(512, 4) void mega_kernel(
    const float* __restrict__ x,
    const unsigned short* __restrict__ wt,
    const unsigned short* __restrict__ at,
    const float* __restrict__ gamma, const float* __restrict__ beta,
    const float* __restrict__ mean, const float* __restrict__ var,
    float* __restrict__ out) {
    // swizzle: hardware round-robins linear id over 8 XCDs (id%8 = XCD)
    const int lin = blockIdx.x + 38 * blockIdx.y;        // 0..607, grid (38,16)
    const int logical = (lin & 7) * 76 + (lin >> 3);     // bijective (608 = 8*76)
    const int ch = logical % 38;
    const int n0 = (logical / 38) * 2;

    const int l0 = ch * 8;
    const int tid = threadIdx.x;
    const int wv = tid >> 6, lane = tid & 63, q = lane >> 4, lcol = lane & 15;

    __shared__ __align__(16) short smem[13312];   // xwL (13248) aliased with Ys (13312)
    __shared__ float scs[64], shs[64];

    const float* xn0 = x + (size_t)n0 * 480000;
    float* outn0 = out + (size_t)n0 * 480000;

    // b2 fragments (at, L2-resident) + BN constants
    bf16x8 b2[2][3];
    #pragma unroll
    for (int nt = 0; nt < 2; ++nt)
        #pragma unroll
        for (int s = 0; s < 3; ++s)
            b2[nt][s] = *(const bf16x8*)(at + (size_t)(nt * 16 + lcol) * 96 + 32 * s + 8 * q);
    if (tid < 64) {
        float sc = gamma[tid] * rsqrtf(var[tid] + EPS);
        scs[tid] = sc;
        shs[tid] = beta[tid] - mean[tid] * sc;
    }

    process_sample(xn0, outn0, wt, smem, b2, scs, shs, l0, tid, wv, lane, q, lcol);
    __syncthreads();   // all waves done with Ys(n0); smem becomes xwL(n1)
    process_sample(xn0 + 480000, outn0 + 480000, wt, smem, b2, scs, shs,
                   l0, tid, wv, lane, q, lcol);
}

extern "C" void kernel_launch(void* const* d_in, const int* in_sizes, int n_in,
                              void* d_out, int out_size, void* d_ws, size_t ws_size,
                              hipStream_t stream) {
    const float* x     = (const float*)d_in[0];
    const float* A     = (const float*)d_in[1];
    const float* W     = (const float*)d_in[2];
    const float* gamma = (const float*)d_in[3];
    const float* beta  = (const float*)d_in[4];
    const float* mean  = (const float*)d_in[5];
    const float* var   = (const float*)d_in[6];
    float* out = (float*)d_out;

    char* ws = (char*)d_ws;
    unsigned short* wt = (unsigned short*)ws;               // 24,576 B
    unsigned short* at = (unsigned short*)(ws + 24576);     // 6,144 B

    prep_kernel<<<60, 256, 0, stream>>>(A, W, wt, at);
    mega_kernel<<<dim3(38, 16), 512, 0, stream>>>(x, wt, at, gamma, beta, mean, var, out);
}